// Round 10
// baseline (336.594 us; speedup 1.0000x reference)
//
#include <hip/hip_runtime.h>
#include <hip/hip_bf16.h>
#include <math.h>

#define DIM 256
#define KCODES 8192
#define BN_TOTAL 32768
#define NSPLIT 4

// d_out flat f32 layout (reference return order)
#define OUT_IND 8388608
#define OUT_LOSS 8421376
#define OUT_CS 8421377
#define OUT_ES 8429569
#define OUT_TOTAL 10526721

// scratch-in-output offsets (f32 units)
#define ABUF_OFF 0           // x bf16 [32768][256] = 16 MB, dead after mfma
#define CBB_OFF 4194304      // cb bf16 [8192][256] (swizzled) = 4 MB, dead after mfma
#define PART_OFF OUT_ES      // partials float2[32768][8] = 2 MB, dead after pick

typedef unsigned short u16;
typedef unsigned int u32;
typedef __attribute__((ext_vector_type(8))) short bf16x8;
typedef __attribute__((ext_vector_type(4))) float f32x4;
typedef __attribute__((address_space(1))) const void gvoid_t;
typedef __attribute__((address_space(3))) void lvoid_t;

// ---------------- prep: x -> bf16 hi; cb -> bf16 hi (chunk-swizzled) + c2 ----
__global__ __launch_bounds__(256) void vq_prep(const float* __restrict__ x,
                                               const float* __restrict__ cb,
                                               u16* __restrict__ A,
                                               u16* __restrict__ B,
                                               float* __restrict__ c2,
                                               float* __restrict__ c2m) {
  int b = blockIdx.x;
  if (b < 4096) {
    int g = b * 256 + threadIdx.x;
    int row = g >> 5;
    int d0 = (g & 31) * 8;
    float4 v0 = *(const float4*)(x + (size_t)row * DIM + d0);
    float4 v1 = *(const float4*)(x + (size_t)row * DIM + d0 + 4);
    float vv[8] = {v0.x, v0.y, v0.z, v0.w, v1.x, v1.y, v1.z, v1.w};
    u16 h[8];
#pragma unroll
    for (int i = 0; i < 8; ++i) {
      __hip_bfloat16 bb = __float2bfloat16(vv[i]);
      h[i] = *reinterpret_cast<u16*>(&bb);
    }
    uint4 hv;
    hv.x = (u32)h[0] | ((u32)h[1] << 16); hv.y = (u32)h[2] | ((u32)h[3] << 16);
    hv.z = (u32)h[4] | ((u32)h[5] << 16); hv.w = (u32)h[6] | ((u32)h[7] << 16);
    *(uint4*)(A + (size_t)row * DIM + d0) = hv;
  } else {
    int g = (b - 4096) * 256 + threadIdx.x;
    int code = g >> 5;
    int l5 = g & 31;
    int d0 = l5 * 8;
    float4 v0 = *(const float4*)(cb + (size_t)code * DIM + d0);
    float4 v1 = *(const float4*)(cb + (size_t)code * DIM + d0 + 4);
    float vv[8] = {v0.x, v0.y, v0.z, v0.w, v1.x, v1.y, v1.z, v1.w};
    u16 h[8];
    float s = 0.0f;
#pragma unroll
    for (int i = 0; i < 8; ++i) {
      __hip_bfloat16 bb = __float2bfloat16(vv[i]);
      h[i] = *reinterpret_cast<u16*>(&bb);
      s += vv[i] * vv[i];
    }
    uint4 hv;
    hv.x = (u32)h[0] | ((u32)h[1] << 16); hv.y = (u32)h[2] | ((u32)h[3] << 16);
    hv.z = (u32)h[4] | ((u32)h[5] << 16); hv.w = (u32)h[6] | ((u32)h[7] << 16);
    // chunk swizzle: 16B chunk j of each 32-k group stored at j ^ ((code>>1)&3)
    int j = l5 & 3;
    int js = j ^ ((code >> 1) & 3);
    int d0s = ((l5 & ~3) | js) * 8;
    *(uint4*)(B + (size_t)code * DIM + d0s) = hv;
#pragma unroll
    for (int m = 1; m <= 16; m <<= 1) s += __shfl_xor(s, m, 64);
    if (l5 == 0) { c2[code] = s; c2m[code] = s - 256.0f; }
  }
}

// ---------------- main: K=256 bf16 MFMA + packed-key top-2 argmin ----------
// Round-9 structure; changes: __launch_bounds__(256,4) for 4 blocks/CU
// cross-block phase overlap, and s_setprio(1) around the MFMA cluster (T5).
__global__ __launch_bounds__(256, 4)
void vq_mfma(const u16* __restrict__ XB, const u16* __restrict__ CBb,
             const float* __restrict__ c2m, float2* __restrict__ partials) {
  __shared__ __align__(16) u16 As[2][4096];
  const int t = threadIdx.x;
  const int wid = t >> 6;
  const int lane = t & 63;
  const int lhi = lane >> 4, llo = lane & 15;
  const int sl = lhi ^ ((llo >> 1) & 3);
  const int rt = blockIdx.x & 255;
  const int s = blockIdx.x >> 8;
  const int row0 = rt * 128;
  const int code0base = s * (KCODES / NSPLIT);

  bf16x8 b[2][8];
#pragma unroll
  for (int n = 0; n < 2; ++n) {
    const u16* bp = XB + (size_t)(row0 + wid * 32 + n * 16 + llo) * DIM + lhi * 8;
#pragma unroll
    for (int ks = 0; ks < 8; ++ks)
      b[n][ks] = *(const bf16x8*)(bp + ks * 32);
  }

  char* AsB = (char*)As;
  const int r0 = t >> 2, c80 = (t & 3) << 3;
  const int r1 = 64 + r0;

  float v1[2], v2[2];
#pragma unroll
  for (int n = 0; n < 2; ++n) { v1[n] = INFINITY; v2[n] = INFINITY; }

  {
    const u16* sa0 = CBb + (size_t)(code0base + r0) * DIM + c80;
    const u16* sa1 = CBb + (size_t)(code0base + r1) * DIM + c80;
    __builtin_amdgcn_global_load_lds((gvoid_t*)sa0, (lvoid_t*)(AsB + (wid << 10)), 16, 0, 0);
    __builtin_amdgcn_global_load_lds((gvoid_t*)sa1, (lvoid_t*)(AsB + 4096 + (wid << 10)), 16, 0, 0);
  }
  __syncthreads();

#pragma unroll 1
  for (int ct = 0; ct < 16; ++ct) {
    const int code0 = code0base + ct * 128;
    f32x4 acc[8][2];
#pragma unroll
    for (int m = 0; m < 8; ++m)
#pragma unroll
      for (int n = 0; n < 2; ++n) acc[m][n] = (f32x4){0.f, 0.f, 0.f, 0.f};

#pragma unroll
    for (int ks = 0; ks < 8; ++ks) {
      const int cur = ks & 1;
      if (!(ct == 15 && ks == 7)) {
        const int nct = (ks == 7) ? ct + 1 : ct;
        const int nks = (ks == 7) ? 0 : ks + 1;
        const u16* sa0 = CBb + (size_t)(code0base + nct * 128 + r0) * DIM + nks * 32 + c80;
        const u16* sa1 = CBb + (size_t)(code0base + nct * 128 + r1) * DIM + nks * 32 + c80;
        char* dst = AsB + ((cur ^ 1) << 13);
        __builtin_amdgcn_global_load_lds((gvoid_t*)sa0, (lvoid_t*)(dst + (wid << 10)), 16, 0, 0);
        __builtin_amdgcn_global_load_lds((gvoid_t*)sa1, (lvoid_t*)(dst + 4096 + (wid << 10)), 16, 0, 0);
      }
      const char* src = AsB + (cur << 13);
      bf16x8 a[8];
#pragma unroll
      for (int m = 0; m < 8; ++m)
        a[m] = *(const bf16x8*)(src + (((m * 16 + llo) << 6) + (sl << 4)));
      __builtin_amdgcn_s_setprio(1);
#pragma unroll
      for (int m = 0; m < 8; ++m) {
        acc[m][0] = __builtin_amdgcn_mfma_f32_16x16x32_bf16(a[m], b[0][ks], acc[m][0], 0, 0, 0);
        acc[m][1] = __builtin_amdgcn_mfma_f32_16x16x32_bf16(a[m], b[1][ks], acc[m][1], 0, 0, 0);
      }
      __builtin_amdgcn_s_setprio(0);
      if (ks == 7) {
#pragma unroll
        for (int m = 0; m < 8; ++m) {
          int cbase = code0 + m * 16 + lhi * 4;
          float4 cv = *(const float4*)(c2m + cbase);
          float cvv[4] = {cv.x, cv.y, cv.z, cv.w};
#pragma unroll
          for (int n = 0; n < 2; ++n) {
#pragma unroll
            for (int r = 0; r < 4; ++r) {
              float d = fmaf(-2.0f, acc[m][n][r], cvv[r]);
              float key = __uint_as_float((__float_as_uint(d) & ~0x1FFFu) |
                                          (u32)(cbase + r));
              float lo = fminf(key, v1[n]);
              float hi = fmaxf(key, v1[n]);
              v1[n] = lo;
              v2[n] = fminf(v2[n], hi);
            }
          }
        }
      }
      __syncthreads();
    }
  }
#pragma unroll
  for (int n = 0; n < 2; ++n) {
    float w1 = __shfl_xor(v1[n], 16, 64);
    float w2 = __shfl_xor(v2[n], 16, 64);
    float m1 = fminf(v1[n], w1);
    float m2 = fminf(fmaxf(v1[n], w1), fminf(v2[n], w2));
    if ((lhi & 1) == 0) {
      int row = row0 + wid * 32 + n * 16 + llo;
      int gslot = lhi >> 1;
      partials[(size_t)row * 8 + s * 2 + gslot] = make_float2(m1, m2);
    }
  }
}

// ---- pick: 16 cands -> top-4 -> exact rescore -> ind/out_ind/out_q/hist ----
__global__ __launch_bounds__(256)
void vq_pick(const float* __restrict__ x, const float* __restrict__ cb,
             const float* __restrict__ c2g, const float2* __restrict__ partials,
             int* __restrict__ ind, float* __restrict__ out_ind,
             float* __restrict__ out_q, int* __restrict__ cnt,
             float* __restrict__ loss_part) {
  __shared__ float lsm[4];
  int wid = threadIdx.x >> 6, lane = threadIdx.x & 63;
  int row = blockIdx.x * 4 + wid;
  float cv = INFINITY, cv2 = INFINITY;
  if (lane < 8) {
    float2 p = partials[(size_t)row * 8 + lane];
    cv = p.x; cv2 = p.y;
  }
  int cand[4];
#pragma unroll
  for (int rsel = 0; rsel < 4; ++rsel) {
    float bv = cv;
#pragma unroll
    for (int mask = 1; mask < 8; mask <<= 1)
      bv = fminf(bv, __shfl_xor(bv, mask, 64));
    bv = __shfl(bv, 0, 64);
    cand[rsel] = (int)(__float_as_uint(bv) & 8191u);
    if (cv == bv) { cv = cv2; cv2 = INFINITY; }
  }
  const float4 xv = *(const float4*)(x + (size_t)row * DIM + lane * 4);
  float4 q0 = *(const float4*)(cb + (size_t)cand[0] * DIM + lane * 4);
  float4 q1 = *(const float4*)(cb + (size_t)cand[1] * DIM + lane * 4);
  float4 q2 = *(const float4*)(cb + (size_t)cand[2] * DIM + lane * 4);
  float4 q3 = *(const float4*)(cb + (size_t)cand[3] * DIM + lane * 4);
  float d0 = xv.x * q0.x + xv.y * q0.y + xv.z * q0.z + xv.w * q0.w;
  float d1 = xv.x * q1.x + xv.y * q1.y + xv.z * q1.z + xv.w * q1.w;
  float d2 = xv.x * q2.x + xv.y * q2.y + xv.z * q2.z + xv.w * q2.w;
  float d3 = xv.x * q3.x + xv.y * q3.y + xv.z * q3.z + xv.w * q3.w;
  float x2 = xv.x * xv.x + xv.y * xv.y + xv.z * xv.z + xv.w * xv.w;
#pragma unroll
  for (int mask = 1; mask < 64; mask <<= 1) {
    d0 += __shfl_xor(d0, mask, 64);
    d1 += __shfl_xor(d1, mask, 64);
    d2 += __shfl_xor(d2, mask, 64);
    d3 += __shfl_xor(d3, mask, 64);
    x2 += __shfl_xor(x2, mask, 64);
  }
  float e0 = fmaf(-2.0f, d0, c2g[cand[0]]);
  float e1 = fmaf(-2.0f, d1, c2g[cand[1]]);
  float e2 = fmaf(-2.0f, d2, c2g[cand[2]]);
  float e3 = fmaf(-2.0f, d3, c2g[cand[3]]);
  float best = e0; int bk = cand[0];
  if (e1 < best || (e1 == best && cand[1] < bk)) { best = e1; bk = cand[1]; }
  if (e2 < best || (e2 == best && cand[2] < bk)) { best = e2; bk = cand[2]; }
  if (e3 < best || (e3 == best && cand[3] < bk)) { best = e3; bk = cand[3]; }
  float4 q = (bk == cand[1]) ? q1 : (bk == cand[2]) ? q2 : (bk == cand[3]) ? q3 : q0;
  *(float4*)(out_q + (size_t)row * DIM + lane * 4) = q;
  if (lane == 0) {
    ind[row] = bk;
    out_ind[row] = (float)bk;
    atomicAdd(cnt + bk, 1);
    lsm[wid] = x2 + best;   // == ||q - x||^2 (exact identity)
  }
  __syncthreads();
  if (threadIdx.x == 0)
    loss_part[blockIdx.x] = lsm[0] + lsm[1] + lsm[2] + lsm[3];
}

// ---- scan: exclusive scan cnt -> offs/woffs; out_cs; reduce loss ----
__global__ __launch_bounds__(1024)
void vq_scan(const int* __restrict__ cnt, int* __restrict__ offs,
             int* __restrict__ woffs, float* __restrict__ out_cs,
             const float* __restrict__ loss_part, float* __restrict__ out_loss) {
  __shared__ int ssum[1024];
  __shared__ float sls[1024];
  int tid = threadIdx.x;
  int c[8], loc[8];
  int s = 0;
#pragma unroll
  for (int j = 0; j < 8; ++j) {
    c[j] = cnt[tid * 8 + j];
    loc[j] = s;
    s += c[j];
  }
  ssum[tid] = s;
  float ls = 0.0f;
#pragma unroll
  for (int j = 0; j < 8; ++j) ls += loss_part[tid * 8 + j];
  sls[tid] = ls;
  __syncthreads();
  for (int off = 1; off < 1024; off <<= 1) {
    int v = (tid >= off) ? ssum[tid - off] : 0;
    __syncthreads();
    ssum[tid] += v;
    __syncthreads();
  }
  int base = (tid > 0) ? ssum[tid - 1] : 0;
#pragma unroll
  for (int j = 0; j < 8; ++j) {
    int o = base + loc[j];
    offs[tid * 8 + j] = o;
    woffs[tid * 8 + j] = o;
    out_cs[tid * 8 + j] = (float)c[j];
  }
  for (int off = 512; off >= 1; off >>= 1) {
    if (tid < off) sls[tid] += sls[tid + off];
    __syncthreads();
  }
  if (tid == 0) *out_loss = sls[0] * (1.0f / 8388608.0f);
}

// ---- scatter: build rowlist grouped by code ----
__global__ __launch_bounds__(256)
void vq_scatter(const int* __restrict__ ind, int* __restrict__ woffs,
                int* __restrict__ rowlist) {
  int row = blockIdx.x * 256 + threadIdx.x;
  int k = ind[row];
  int pos = atomicAdd(woffs + k, 1);
  rowlist[pos] = row;
}

// ---- esum: ONE BLOCK (4 waves) PER CODE; unroll-4 ILP; LDS cross-wave ----
__global__ __launch_bounds__(256)
void vq_esum(const float* __restrict__ x, const int* __restrict__ offs,
             const int* __restrict__ cnt, const int* __restrict__ rowlist,
             float* __restrict__ out_es) {
  __shared__ float4 sred[3][64];
  int k = blockIdx.x;
  int wid = threadIdx.x >> 6, lane = threadIdx.x & 63;
  int start = offs[k], n = cnt[k];
  const int* rl = rowlist + start;
  int jb = (n * wid) >> 2, je = (n * (wid + 1)) >> 2;
  float4 acc = {0.f, 0.f, 0.f, 0.f};
  int j = jb;
  for (; j + 4 <= je; j += 4) {
    int r0 = rl[j], r1 = rl[j + 1], r2 = rl[j + 2], r3 = rl[j + 3];
    float4 v0 = *(const float4*)(x + (size_t)r0 * DIM + lane * 4);
    float4 v1 = *(const float4*)(x + (size_t)r1 * DIM + lane * 4);
    float4 v2 = *(const float4*)(x + (size_t)r2 * DIM + lane * 4);
    float4 v3 = *(const float4*)(x + (size_t)r3 * DIM + lane * 4);
    acc.x += v0.x + v1.x + v2.x + v3.x;
    acc.y += v0.y + v1.y + v2.y + v3.y;
    acc.z += v0.z + v1.z + v2.z + v3.z;
    acc.w += v0.w + v1.w + v2.w + v3.w;
  }
  for (; j < je; ++j) {
    int r = rl[j];
    float4 v = *(const float4*)(x + (size_t)r * DIM + lane * 4);
    acc.x += v.x; acc.y += v.y; acc.z += v.z; acc.w += v.w;
  }
  if (wid > 0) sred[wid - 1][lane] = acc;
  __syncthreads();
  if (wid == 0) {
    float4 a1 = sred[0][lane], a2 = sred[1][lane], a3 = sred[2][lane];
    acc.x += a1.x + a2.x + a3.x;
    acc.y += a1.y + a2.y + a3.y;
    acc.z += a1.z + a2.z + a3.z;
    acc.w += a1.w + a2.w + a3.w;
    *(float4*)(out_es + (size_t)k * DIM + lane * 4) = acc;
  }
}

extern "C" void kernel_launch(void* const* d_in, const int* in_sizes, int n_in,
                              void* d_out, int out_size, void* d_ws,
                              size_t ws_size, hipStream_t stream) {
  const float* x = (const float*)d_in[0];
  const float* cb = (const float*)d_in[1];
  float* out = (float*)d_out;
  float* out_q = out;
  float* out_ind = out + OUT_IND;
  float* out_loss = out + OUT_LOSS;
  float* out_cs = out + OUT_CS;
  float* out_es = out + OUT_ES;

  // Scratch-in-output (same proven layout as rounds 7-9):
  u16* Abuf = (u16*)(out + ABUF_OFF);
  u16* CBb = (u16*)(out + CBB_OFF);
  float2* partials = (float2*)(out + PART_OFF);

  // ws layout (448 KB; >= 2.21 MB proven available in round 1)
  char* w = (char*)d_ws;
  int* cnt = (int*)w;                              // 32 KB [memset 0]
  int* offs = (int*)(w + (32 << 10));              // 32 KB
  int* woffs = (int*)(w + (64 << 10));             // 32 KB
  float* loss_part = (float*)(w + (96 << 10));     // 32 KB
  int* ind = (int*)(w + (128 << 10));              // 128 KB
  int* rowlist = (int*)(w + (256 << 10));          // 128 KB
  float* c2 = (float*)(w + (384 << 10));           // 32 KB
  float* c2m = (float*)(w + (416 << 10));          // 32 KB

  hipMemsetAsync(cnt, 0, KCODES * sizeof(int), stream);
  vq_prep<<<5120, 256, 0, stream>>>(x, cb, Abuf, CBb, c2, c2m);
  vq_mfma<<<256 * NSPLIT, 256, 0, stream>>>(Abuf, CBb, c2m, partials);
  vq_pick<<<BN_TOTAL / 4, 256, 0, stream>>>(x, cb, c2, partials, ind, out_ind,
                                            out_q, cnt, loss_part);
  vq_scan<<<1, 1024, 0, stream>>>(cnt, offs, woffs, out_cs, loss_part, out_loss);
  vq_scatter<<<BN_TOTAL / 256, 256, 0, stream>>>(ind, woffs, rowlist);
  vq_esum<<<KCODES, 256, 0, stream>>>(x, offs, cnt, rowlist, out_es);
}

// Round 11
// 230.970 us; speedup vs baseline: 1.4573x; 1.4573x over previous
//
#include <hip/hip_runtime.h>
#include <hip/hip_bf16.h>
#include <math.h>

#define DIM 256
#define KCODES 8192
#define BN_TOTAL 32768
#define NSPLIT 4

// d_out flat f32 layout (reference return order)
#define OUT_IND 8388608
#define OUT_LOSS 8421376
#define OUT_CS 8421377
#define OUT_ES 8429569
#define OUT_TOTAL 10526721

// scratch-in-output offsets (f32 units)
#define ABUF_OFF 0           // x bf16 [32768][256] = 16 MB, dead after mfma
#define CBB_OFF 4194304      // cb bf16 [8192][256] (swizzled) = 4 MB, dead after mfma
#define PART_OFF OUT_ES      // partials float2[32768][16] = 4 MB, dead after pick

typedef unsigned short u16;
typedef unsigned int u32;
typedef __attribute__((ext_vector_type(8))) short bf16x8;
typedef __attribute__((ext_vector_type(4))) float f32x4;
typedef __attribute__((address_space(1))) const void gvoid_t;
typedef __attribute__((address_space(3))) void lvoid_t;

// ---------------- prep: x -> bf16 hi; cb -> bf16 hi (chunk-swizzled) + c2 ----
__global__ __launch_bounds__(256) void vq_prep(const float* __restrict__ x,
                                               const float* __restrict__ cb,
                                               u16* __restrict__ A,
                                               u16* __restrict__ B,
                                               float* __restrict__ c2,
                                               float* __restrict__ c2m) {
  int b = blockIdx.x;
  if (b < 4096) {
    int g = b * 256 + threadIdx.x;
    int row = g >> 5;
    int d0 = (g & 31) * 8;
    float4 v0 = *(const float4*)(x + (size_t)row * DIM + d0);
    float4 v1 = *(const float4*)(x + (size_t)row * DIM + d0 + 4);
    float vv[8] = {v0.x, v0.y, v0.z, v0.w, v1.x, v1.y, v1.z, v1.w};
    u16 h[8];
#pragma unroll
    for (int i = 0; i < 8; ++i) {
      __hip_bfloat16 bb = __float2bfloat16(vv[i]);
      h[i] = *reinterpret_cast<u16*>(&bb);
    }
    uint4 hv;
    hv.x = (u32)h[0] | ((u32)h[1] << 16); hv.y = (u32)h[2] | ((u32)h[3] << 16);
    hv.z = (u32)h[4] | ((u32)h[5] << 16); hv.w = (u32)h[6] | ((u32)h[7] << 16);
    *(uint4*)(A + (size_t)row * DIM + d0) = hv;
  } else {
    int g = (b - 4096) * 256 + threadIdx.x;
    int code = g >> 5;
    int l5 = g & 31;
    int d0 = l5 * 8;
    float4 v0 = *(const float4*)(cb + (size_t)code * DIM + d0);
    float4 v1 = *(const float4*)(cb + (size_t)code * DIM + d0 + 4);
    float vv[8] = {v0.x, v0.y, v0.z, v0.w, v1.x, v1.y, v1.z, v1.w};
    u16 h[8];
    float s = 0.0f;
#pragma unroll
    for (int i = 0; i < 8; ++i) {
      __hip_bfloat16 bb = __float2bfloat16(vv[i]);
      h[i] = *reinterpret_cast<u16*>(&bb);
      s += vv[i] * vv[i];
    }
    uint4 hv;
    hv.x = (u32)h[0] | ((u32)h[1] << 16); hv.y = (u32)h[2] | ((u32)h[3] << 16);
    hv.z = (u32)h[4] | ((u32)h[5] << 16); hv.w = (u32)h[6] | ((u32)h[7] << 16);
    // chunk swizzle: 16B chunk j of each 32-k group stored at j ^ ((code>>1)&3)
    int j = l5 & 3;
    int js = j ^ ((code >> 1) & 3);
    int d0s = ((l5 & ~3) | js) * 8;
    *(uint4*)(B + (size_t)code * DIM + d0s) = hv;
#pragma unroll
    for (int m = 1; m <= 16; m <<= 1) s += __shfl_xor(s, m, 64);
    if (l5 == 0) { c2[code] = s; c2m[code] = s - 256.0f; }
  }
}

// ---------------- main: K=256 bf16 MFMA + packed-key top-2 argmin ----------
// 2x2 wave split: wave (wm,wn) owns 64 codes x 64 rows of the 128x128 tile.
// Halves redundant A-tile LDS reads vs rows-only split (each a-frag byte now
// read by 2 waves, not 4). b[4][8] x-fragments in registers (~128 VGPR);
// occupancy target unchanged at 2 blocks/CU (round-10 lesson: never buy
// occupancy with B's registers -> FETCH_SIZE exploded 17x).
__global__ __launch_bounds__(256, 2)
void vq_mfma(const u16* __restrict__ XB, const u16* __restrict__ CBb,
             const float* __restrict__ c2m, float2* __restrict__ partials) {
  __shared__ __align__(16) u16 As[2][4096];
  const int t = threadIdx.x;
  const int wid = t >> 6;
  const int lane = t & 63;
  const int lhi = lane >> 4, llo = lane & 15;
  const int sl = lhi ^ ((llo >> 1) & 3);
  const int wm = wid & 1;    // code half (0..1)
  const int wn = wid >> 1;   // row half (0..1)
  const int rt = blockIdx.x & 255;
  const int s = blockIdx.x >> 8;
  const int row0 = rt * 128;
  const int code0base = s * (KCODES / NSPLIT);

  // preload x fragments: b[n][ks] = row (row0+wn*64+n*16+llo), k = ks*32+lhi*8
  bf16x8 b[4][8];
#pragma unroll
  for (int n = 0; n < 4; ++n) {
    const u16* bp = XB + (size_t)(row0 + wn * 64 + n * 16 + llo) * DIM + lhi * 8;
#pragma unroll
    for (int ks = 0; ks < 8; ++ks)
      b[n][ks] = *(const bf16x8*)(bp + ks * 32);
  }

  char* AsB = (char*)As;
  const int r0 = t >> 2, c80 = (t & 3) << 3;
  const int r1 = 64 + r0;

  float v1[4], v2[4];
#pragma unroll
  for (int n = 0; n < 4; ++n) { v1[n] = INFINITY; v2[n] = INFINITY; }

  {
    const u16* sa0 = CBb + (size_t)(code0base + r0) * DIM + c80;
    const u16* sa1 = CBb + (size_t)(code0base + r1) * DIM + c80;
    __builtin_amdgcn_global_load_lds((gvoid_t*)sa0, (lvoid_t*)(AsB + (wid << 10)), 16, 0, 0);
    __builtin_amdgcn_global_load_lds((gvoid_t*)sa1, (lvoid_t*)(AsB + 4096 + (wid << 10)), 16, 0, 0);
  }
  __syncthreads();

#pragma unroll 1
  for (int ct = 0; ct < 16; ++ct) {
    const int code0 = code0base + ct * 128;
    f32x4 acc[4][4];
#pragma unroll
    for (int m = 0; m < 4; ++m)
#pragma unroll
      for (int n = 0; n < 4; ++n) acc[m][n] = (f32x4){0.f, 0.f, 0.f, 0.f};

#pragma unroll
    for (int ks = 0; ks < 8; ++ks) {
      const int cur = ks & 1;
      if (!(ct == 15 && ks == 7)) {
        const int nct = (ks == 7) ? ct + 1 : ct;
        const int nks = (ks == 7) ? 0 : ks + 1;
        const u16* sa0 = CBb + (size_t)(code0base + nct * 128 + r0) * DIM + nks * 32 + c80;
        const u16* sa1 = CBb + (size_t)(code0base + nct * 128 + r1) * DIM + nks * 32 + c80;
        char* dst = AsB + ((cur ^ 1) << 13);
        __builtin_amdgcn_global_load_lds((gvoid_t*)sa0, (lvoid_t*)(dst + (wid << 10)), 16, 0, 0);
        __builtin_amdgcn_global_load_lds((gvoid_t*)sa1, (lvoid_t*)(dst + 4096 + (wid << 10)), 16, 0, 0);
      }
      const char* src = AsB + (cur << 13);
      bf16x8 a[4];
#pragma unroll
      for (int m = 0; m < 4; ++m)
        a[m] = *(const bf16x8*)(src + (((wm * 64 + m * 16 + llo) << 6) + (sl << 4)));
#pragma unroll
      for (int m = 0; m < 4; ++m)
#pragma unroll
        for (int n = 0; n < 4; ++n)
          acc[m][n] = __builtin_amdgcn_mfma_f32_16x16x32_bf16(a[m], b[n][ks], acc[m][n], 0, 0, 0);
      if (ks == 7) {
        // dist-256 = c2m - 2*dot; pack code into low 13 mantissa bits; top-2
#pragma unroll
        for (int m = 0; m < 4; ++m) {
          int cbase = code0 + wm * 64 + m * 16 + lhi * 4;
          float4 cv = *(const float4*)(c2m + cbase);
          float cvv[4] = {cv.x, cv.y, cv.z, cv.w};
#pragma unroll
          for (int n = 0; n < 4; ++n) {
#pragma unroll
            for (int r = 0; r < 4; ++r) {
              float d = fmaf(-2.0f, acc[m][n][r], cvv[r]);
              float key = __uint_as_float((__float_as_uint(d) & ~0x1FFFu) |
                                          (u32)(cbase + r));
              float lo = fminf(key, v1[n]);
              float hi = fmaxf(key, v1[n]);
              v1[n] = lo;
              v2[n] = fminf(v2[n], hi);
            }
          }
        }
      }
      __syncthreads();
    }
  }
  // merge lhi pairs (0<->1, 2<->3); unique slot per (split, wm, lhi-pair):
  // 16 slots/row, each = top-2 of a disjoint 512-code slice.
#pragma unroll
  for (int n = 0; n < 4; ++n) {
    float w1 = __shfl_xor(v1[n], 16, 64);
    float w2 = __shfl_xor(v2[n], 16, 64);
    float m1 = fminf(v1[n], w1);
    float m2 = fminf(fmaxf(v1[n], w1), fminf(v2[n], w2));
    if ((lhi & 1) == 0) {
      int row = row0 + wn * 64 + n * 16 + llo;
      int slot = s * 4 + wm * 2 + (lhi >> 1);
      partials[(size_t)row * 16 + slot] = make_float2(m1, m2);
    }
  }
}

// ---- pick: 32 cands -> top-4 -> exact rescore -> ind/out_ind/out_q/hist ----
__global__ __launch_bounds__(256)
void vq_pick(const float* __restrict__ x, const float* __restrict__ cb,
             const float* __restrict__ c2g, const float2* __restrict__ partials,
             int* __restrict__ ind, float* __restrict__ out_ind,
             float* __restrict__ out_q, int* __restrict__ cnt,
             float* __restrict__ loss_part) {
  __shared__ float lsm[4];
  int wid = threadIdx.x >> 6, lane = threadIdx.x & 63;
  int row = blockIdx.x * 4 + wid;
  float cv = INFINITY, cv2 = INFINITY;
  if (lane < 16) {
    float2 p = partials[(size_t)row * 16 + lane];
    cv = p.x; cv2 = p.y;
  }
  int cand[4];
#pragma unroll
  for (int rsel = 0; rsel < 4; ++rsel) {
    float bv = cv;
#pragma unroll
    for (int mask = 1; mask < 16; mask <<= 1)
      bv = fminf(bv, __shfl_xor(bv, mask, 64));
    bv = __shfl(bv, 0, 64);
    cand[rsel] = (int)(__float_as_uint(bv) & 8191u);
    if (cv == bv) { cv = cv2; cv2 = INFINITY; }
  }
  const float4 xv = *(const float4*)(x + (size_t)row * DIM + lane * 4);
  float4 q0 = *(const float4*)(cb + (size_t)cand[0] * DIM + lane * 4);
  float4 q1 = *(const float4*)(cb + (size_t)cand[1] * DIM + lane * 4);
  float4 q2 = *(const float4*)(cb + (size_t)cand[2] * DIM + lane * 4);
  float4 q3 = *(const float4*)(cb + (size_t)cand[3] * DIM + lane * 4);
  float d0 = xv.x * q0.x + xv.y * q0.y + xv.z * q0.z + xv.w * q0.w;
  float d1 = xv.x * q1.x + xv.y * q1.y + xv.z * q1.z + xv.w * q1.w;
  float d2 = xv.x * q2.x + xv.y * q2.y + xv.z * q2.z + xv.w * q2.w;
  float d3 = xv.x * q3.x + xv.y * q3.y + xv.z * q3.z + xv.w * q3.w;
  float x2 = xv.x * xv.x + xv.y * xv.y + xv.z * xv.z + xv.w * xv.w;
#pragma unroll
  for (int mask = 1; mask < 64; mask <<= 1) {
    d0 += __shfl_xor(d0, mask, 64);
    d1 += __shfl_xor(d1, mask, 64);
    d2 += __shfl_xor(d2, mask, 64);
    d3 += __shfl_xor(d3, mask, 64);
    x2 += __shfl_xor(x2, mask, 64);
  }
  float e0 = fmaf(-2.0f, d0, c2g[cand[0]]);
  float e1 = fmaf(-2.0f, d1, c2g[cand[1]]);
  float e2 = fmaf(-2.0f, d2, c2g[cand[2]]);
  float e3 = fmaf(-2.0f, d3, c2g[cand[3]]);
  float best = e0; int bk = cand[0];
  if (e1 < best || (e1 == best && cand[1] < bk)) { best = e1; bk = cand[1]; }
  if (e2 < best || (e2 == best && cand[2] < bk)) { best = e2; bk = cand[2]; }
  if (e3 < best || (e3 == best && cand[3] < bk)) { best = e3; bk = cand[3]; }
  float4 q = (bk == cand[1]) ? q1 : (bk == cand[2]) ? q2 : (bk == cand[3]) ? q3 : q0;
  *(float4*)(out_q + (size_t)row * DIM + lane * 4) = q;
  if (lane == 0) {
    ind[row] = bk;
    out_ind[row] = (float)bk;
    atomicAdd(cnt + bk, 1);
    lsm[wid] = x2 + best;   // == ||q - x||^2 (exact identity)
  }
  __syncthreads();
  if (threadIdx.x == 0)
    loss_part[blockIdx.x] = lsm[0] + lsm[1] + lsm[2] + lsm[3];
}

// ---- scan: exclusive scan cnt -> offs/woffs; out_cs; reduce loss ----
__global__ __launch_bounds__(1024)
void vq_scan(const int* __restrict__ cnt, int* __restrict__ offs,
             int* __restrict__ woffs, float* __restrict__ out_cs,
             const float* __restrict__ loss_part, float* __restrict__ out_loss) {
  __shared__ int ssum[1024];
  __shared__ float sls[1024];
  int tid = threadIdx.x;
  int c[8], loc[8];
  int s = 0;
#pragma unroll
  for (int j = 0; j < 8; ++j) {
    c[j] = cnt[tid * 8 + j];
    loc[j] = s;
    s += c[j];
  }
  ssum[tid] = s;
  float ls = 0.0f;
#pragma unroll
  for (int j = 0; j < 8; ++j) ls += loss_part[tid * 8 + j];
  sls[tid] = ls;
  __syncthreads();
  for (int off = 1; off < 1024; off <<= 1) {
    int v = (tid >= off) ? ssum[tid - off] : 0;
    __syncthreads();
    ssum[tid] += v;
    __syncthreads();
  }
  int base = (tid > 0) ? ssum[tid - 1] : 0;
#pragma unroll
  for (int j = 0; j < 8; ++j) {
    int o = base + loc[j];
    offs[tid * 8 + j] = o;
    woffs[tid * 8 + j] = o;
    out_cs[tid * 8 + j] = (float)c[j];
  }
  for (int off = 512; off >= 1; off >>= 1) {
    if (tid < off) sls[tid] += sls[tid + off];
    __syncthreads();
  }
  if (tid == 0) *out_loss = sls[0] * (1.0f / 8388608.0f);
}

// ---- scatter: build rowlist grouped by code ----
__global__ __launch_bounds__(256)
void vq_scatter(const int* __restrict__ ind, int* __restrict__ woffs,
                int* __restrict__ rowlist) {
  int row = blockIdx.x * 256 + threadIdx.x;
  int k = ind[row];
  int pos = atomicAdd(woffs + k, 1);
  rowlist[pos] = row;
}

// ---- esum: ONE BLOCK (4 waves) PER CODE; unroll-4 ILP; LDS cross-wave ----
__global__ __launch_bounds__(256)
void vq_esum(const float* __restrict__ x, const int* __restrict__ offs,
             const int* __restrict__ cnt, const int* __restrict__ rowlist,
             float* __restrict__ out_es) {
  __shared__ float4 sred[3][64];
  int k = blockIdx.x;
  int wid = threadIdx.x >> 6, lane = threadIdx.x & 63;
  int start = offs[k], n = cnt[k];
  const int* rl = rowlist + start;
  int jb = (n * wid) >> 2, je = (n * (wid + 1)) >> 2;
  float4 acc = {0.f, 0.f, 0.f, 0.f};
  int j = jb;
  for (; j + 4 <= je; j += 4) {
    int r0 = rl[j], r1 = rl[j + 1], r2 = rl[j + 2], r3 = rl[j + 3];
    float4 v0 = *(const float4*)(x + (size_t)r0 * DIM + lane * 4);
    float4 v1 = *(const float4*)(x + (size_t)r1 * DIM + lane * 4);
    float4 v2 = *(const float4*)(x + (size_t)r2 * DIM + lane * 4);
    float4 v3 = *(const float4*)(x + (size_t)r3 * DIM + lane * 4);
    acc.x += v0.x + v1.x + v2.x + v3.x;
    acc.y += v0.y + v1.y + v2.y + v3.y;
    acc.z += v0.z + v1.z + v2.z + v3.z;
    acc.w += v0.w + v1.w + v2.w + v3.w;
  }
  for (; j < je; ++j) {
    int r = rl[j];
    float4 v = *(const float4*)(x + (size_t)r * DIM + lane * 4);
    acc.x += v.x; acc.y += v.y; acc.z += v.z; acc.w += v.w;
  }
  if (wid > 0) sred[wid - 1][lane] = acc;
  __syncthreads();
  if (wid == 0) {
    float4 a1 = sred[0][lane], a2 = sred[1][lane], a3 = sred[2][lane];
    acc.x += a1.x + a2.x + a3.x;
    acc.y += a1.y + a2.y + a3.y;
    acc.z += a1.z + a2.z + a3.z;
    acc.w += a1.w + a2.w + a3.w;
    *(float4*)(out_es + (size_t)k * DIM + lane * 4) = acc;
  }
}

extern "C" void kernel_launch(void* const* d_in, const int* in_sizes, int n_in,
                              void* d_out, int out_size, void* d_ws,
                              size_t ws_size, hipStream_t stream) {
  const float* x = (const float*)d_in[0];
  const float* cb = (const float*)d_in[1];
  float* out = (float*)d_out;
  float* out_q = out;
  float* out_ind = out + OUT_IND;
  float* out_loss = out + OUT_LOSS;
  float* out_cs = out + OUT_CS;
  float* out_es = out + OUT_ES;

  // Scratch-in-output (same proven layout; partials now 4 MB in out_es region):
  u16* Abuf = (u16*)(out + ABUF_OFF);
  u16* CBb = (u16*)(out + CBB_OFF);
  float2* partials = (float2*)(out + PART_OFF);

  // ws layout (448 KB; >= 2.21 MB proven available in round 1)
  char* w = (char*)d_ws;
  int* cnt = (int*)w;                              // 32 KB [memset 0]
  int* offs = (int*)(w + (32 << 10));              // 32 KB
  int* woffs = (int*)(w + (64 << 10));             // 32 KB
  float* loss_part = (float*)(w + (96 << 10));     // 32 KB
  int* ind = (int*)(w + (128 << 10));              // 128 KB
  int* rowlist = (int*)(w + (256 << 10));          // 128 KB
  float* c2 = (float*)(w + (384 << 10));           // 32 KB
  float* c2m = (float*)(w + (416 << 10));          // 32 KB

  hipMemsetAsync(cnt, 0, KCODES * sizeof(int), stream);
  vq_prep<<<5120, 256, 0, stream>>>(x, cb, Abuf, CBb, c2, c2m);
  vq_mfma<<<256 * NSPLIT, 256, 0, stream>>>(Abuf, CBb, c2m, partials);
  vq_pick<<<BN_TOTAL / 4, 256, 0, stream>>>(x, cb, c2, partials, ind, out_ind,
                                            out_q, cnt, loss_part);
  vq_scan<<<1, 1024, 0, stream>>>(cnt, offs, woffs, out_cs, loss_part, out_loss);
  vq_scatter<<<BN_TOTAL / 256, 256, 0, stream>>>(ind, woffs, rowlist);
  vq_esum<<<KCODES, 256, 0, stream>>>(x, offs, cnt, rowlist, out_es);
}

// Round 13
// 223.721 us; speedup vs baseline: 1.5045x; 1.0324x over previous
//
#include <hip/hip_runtime.h>
#include <hip/hip_bf16.h>
#include <math.h>

#define DIM 256
#define KCODES 8192
#define BN_TOTAL 32768
#define NSPLIT 2

// d_out flat f32 layout (reference return order)
#define OUT_IND 8388608
#define OUT_LOSS 8421376
#define OUT_CS 8421377
#define OUT_ES 8429569
#define OUT_TOTAL 10526721

// scratch-in-output offsets (f32 units)
#define ABUF_OFF 0           // x bf16 [32768][256] = 16 MB, dead after mfma
#define CBB_OFF 4194304      // cb bf16 [8192][256] (swizzled) = 4 MB, dead after mfma
#define PART_OFF OUT_ES      // partials float2[32768][8] = 2 MB, dead after pick

typedef unsigned short u16;
typedef unsigned int u32;
typedef __attribute__((ext_vector_type(8))) short bf16x8;
typedef __attribute__((ext_vector_type(4))) float f32x4;
typedef __attribute__((address_space(1))) const void gvoid_t;
typedef __attribute__((address_space(3))) void lvoid_t;

// ---------------- prep: x -> bf16 hi; cb -> bf16 hi (chunk-swizzled) + c2 ----
__global__ __launch_bounds__(256) void vq_prep(const float* __restrict__ x,
                                               const float* __restrict__ cb,
                                               u16* __restrict__ A,
                                               u16* __restrict__ B,
                                               float* __restrict__ c2,
                                               float* __restrict__ c2m) {
  int b = blockIdx.x;
  if (b < 4096) {
    int g = b * 256 + threadIdx.x;
    int row = g >> 5;
    int d0 = (g & 31) * 8;
    float4 v0 = *(const float4*)(x + (size_t)row * DIM + d0);
    float4 v1 = *(const float4*)(x + (size_t)row * DIM + d0 + 4);
    float vv[8] = {v0.x, v0.y, v0.z, v0.w, v1.x, v1.y, v1.z, v1.w};
    u16 h[8];
#pragma unroll
    for (int i = 0; i < 8; ++i) {
      __hip_bfloat16 bb = __float2bfloat16(vv[i]);
      h[i] = *reinterpret_cast<u16*>(&bb);
    }
    uint4 hv;
    hv.x = (u32)h[0] | ((u32)h[1] << 16); hv.y = (u32)h[2] | ((u32)h[3] << 16);
    hv.z = (u32)h[4] | ((u32)h[5] << 16); hv.w = (u32)h[6] | ((u32)h[7] << 16);
    *(uint4*)(A + (size_t)row * DIM + d0) = hv;
  } else {
    int g = (b - 4096) * 256 + threadIdx.x;
    int code = g >> 5;
    int l5 = g & 31;
    int d0 = l5 * 8;
    float4 v0 = *(const float4*)(cb + (size_t)code * DIM + d0);
    float4 v1 = *(const float4*)(cb + (size_t)code * DIM + d0 + 4);
    float vv[8] = {v0.x, v0.y, v0.z, v0.w, v1.x, v1.y, v1.z, v1.w};
    u16 h[8];
    float s = 0.0f;
#pragma unroll
    for (int i = 0; i < 8; ++i) {
      __hip_bfloat16 bb = __float2bfloat16(vv[i]);
      h[i] = *reinterpret_cast<u16*>(&bb);
      s += vv[i] * vv[i];
    }
    uint4 hv;
    hv.x = (u32)h[0] | ((u32)h[1] << 16); hv.y = (u32)h[2] | ((u32)h[3] << 16);
    hv.z = (u32)h[4] | ((u32)h[5] << 16); hv.w = (u32)h[6] | ((u32)h[7] << 16);
    // chunk swizzle: 16B chunk j of each 32-k group stored at j ^ ((code>>1)&3)
    int j = l5 & 3;
    int js = j ^ ((code >> 1) & 3);
    int d0s = ((l5 & ~3) | js) * 8;
    *(uint4*)(B + (size_t)code * DIM + d0s) = hv;
#pragma unroll
    for (int m = 1; m <= 16; m <<= 1) s += __shfl_xor(s, m, 64);
    if (l5 == 0) { c2[code] = s; c2m[code] = s - 256.0f; }
  }
}

// ---------------- main: BK=64 bf16 MFMA + packed-key top-2 argmin ----------
// r11's proven stage->sync->read->sync pattern, with BK doubled to 64 k-cols
// per barrier-pair (halves barrier-drain count) and NSPLIT=2 (grid 512).
// LDS: [dbuf][half(32k grp)][128 codes][64B] = 32 KB; each half is the exact
// r11 layout -> swizzle & bank pattern unchanged (conflict-free, verified r7).
__global__ __launch_bounds__(256, 2)
void vq_mfma(const u16* __restrict__ XB, const u16* __restrict__ CBb,
             const float* __restrict__ c2m, float2* __restrict__ partials) {
  __shared__ __align__(16) u16 As[2][2][128][32];   // 32 KB
  const int t = threadIdx.x;
  const int wid = t >> 6;
  const int lane = t & 63;
  const int lhi = lane >> 4, llo = lane & 15;
  const int sl = lhi ^ ((llo >> 1) & 3);
  const int wm = wid & 1;    // code half of tile
  const int wn = wid >> 1;   // row half of tile
  const int rt = blockIdx.x & 255;
  const int s = blockIdx.x >> 8;           // 0..1
  const int row0 = rt * 128;
  const int code0base = s * (KCODES / NSPLIT);

  // preload x fragments: b[n][ks] = row (row0+wn*64+n*16+llo), k = ks*32+lhi*8
  bf16x8 b[4][8];
#pragma unroll
  for (int n = 0; n < 4; ++n) {
    const u16* bp = XB + (size_t)(row0 + wn * 64 + n * 16 + llo) * DIM + lhi * 8;
#pragma unroll
    for (int ks = 0; ks < 8; ++ks)
      b[n][ks] = *(const bf16x8*)(bp + ks * 32);
  }

  char* AsB = (char*)As;
  // staging: 4 instr/wave, p = wid*4+i in [0,16): half h=p>>3, 16-code blk
  const int srow = lane >> 2;          // code within 16-code block
  const int scol = (lane & 3) << 3;    // stored-chunk u16 col within 32

  float v1[4], v2[4];
#pragma unroll
  for (int n = 0; n < 4; ++n) { v1[n] = INFINITY; v2[n] = INFINITY; }

  // stage (ct,kb) -> dbuf d.  src col = kb*64 + h*32 + scol (stored layout).
  auto STAGE = [&](int ct, int kb, int d) {
#pragma unroll
    for (int i = 0; i < 4; ++i) {
      const int p = wid * 4 + i;
      const int h = p >> 3;
      const int cblk = (p & 7) * 16;
      const u16* sp = CBb + (size_t)(code0base + ct * 128 + cblk + srow) * DIM +
                      kb * 64 + h * 32 + scol;
      char* dp = AsB + (d << 14) + (p << 10);   // wave-uniform dest
      __builtin_amdgcn_global_load_lds((gvoid_t*)sp, (lvoid_t*)dp, 16, 0, 0);
    }
  };

  STAGE(0, 0, 0);

#pragma unroll 1
  for (int ct = 0; ct < 32; ++ct) {
    const int code0 = code0base + ct * 128;
    f32x4 acc[4][4];
#pragma unroll
    for (int m = 0; m < 4; ++m)
#pragma unroll
      for (int n = 0; n < 4; ++n) acc[m][n] = (f32x4){0.f, 0.f, 0.f, 0.f};

#pragma unroll
    for (int kb = 0; kb < 4; ++kb) {
      const int cc = ct * 4 + kb;
      if (cc < 127) {
        const int nct = (kb == 3) ? ct + 1 : ct;
        const int nkb = (kb == 3) ? 0 : kb + 1;
        STAGE(nct, nkb, (cc + 1) & 1);
      }
      __syncthreads();
      const char* src = AsB + ((cc & 1) << 14);
#pragma unroll
      for (int ksub = 0; ksub < 2; ++ksub) {
        bf16x8 a[4];
#pragma unroll
        for (int m = 0; m < 4; ++m)
          a[m] = *(const bf16x8*)(src + (ksub << 13) +
                                  ((wm * 64 + m * 16 + llo) << 6) + (sl << 4));
#pragma unroll
        for (int m = 0; m < 4; ++m)
#pragma unroll
          for (int n = 0; n < 4; ++n)
            acc[m][n] = __builtin_amdgcn_mfma_f32_16x16x32_bf16(
                a[m], b[n][kb * 2 + ksub], acc[m][n], 0, 0, 0);
      }
      if (kb == 3) {
        // dist-256 = c2m - 2*dot; pack code into low 13 mantissa bits; top-2
#pragma unroll
        for (int m = 0; m < 4; ++m) {
          int cbase = code0 + wm * 64 + m * 16 + lhi * 4;
          float4 cv = *(const float4*)(c2m + cbase);
          float cvv[4] = {cv.x, cv.y, cv.z, cv.w};
#pragma unroll
          for (int n = 0; n < 4; ++n) {
#pragma unroll
            for (int r = 0; r < 4; ++r) {
              float d = fmaf(-2.0f, acc[m][n][r], cvv[r]);
              float key = __uint_as_float((__float_as_uint(d) & ~0x1FFFu) |
                                          (u32)(cbase + r));
              float lo = fminf(key, v1[n]);
              float hi = fmaxf(key, v1[n]);
              v1[n] = lo;
              v2[n] = fminf(v2[n], hi);
            }
          }
        }
      }
      __syncthreads();
    }
  }
  // merge lhi pairs (0<->1, 2<->3); unique slot per (split, wm, lhi-pair):
  // 8 slots/row, each = top-2 of a disjoint 1024-code slice.
#pragma unroll
  for (int n = 0; n < 4; ++n) {
    float w1 = __shfl_xor(v1[n], 16, 64);
    float w2 = __shfl_xor(v2[n], 16, 64);
    float m1 = fminf(v1[n], w1);
    float m2 = fminf(fmaxf(v1[n], w1), fminf(v2[n], w2));
    if ((lhi & 1) == 0) {
      int row = row0 + wn * 64 + n * 16 + llo;
      int slot = s * 4 + wm * 2 + (lhi >> 1);
      partials[(size_t)row * 8 + slot] = make_float2(m1, m2);
    }
  }
}

// ---- pick: 16 cands -> top-4 -> exact rescore -> ind/out_ind/out_q/hist ----
__global__ __launch_bounds__(256)
void vq_pick(const float* __restrict__ x, const float* __restrict__ cb,
             const float* __restrict__ c2g, const float2* __restrict__ partials,
             int* __restrict__ ind, float* __restrict__ out_ind,
             float* __restrict__ out_q, int* __restrict__ cnt,
             float* __restrict__ loss_part) {
  __shared__ float lsm[4];
  int wid = threadIdx.x >> 6, lane = threadIdx.x & 63;
  int row = blockIdx.x * 4 + wid;
  float cv = INFINITY, cv2 = INFINITY;
  if (lane < 8) {
    float2 p = partials[(size_t)row * 8 + lane];
    cv = p.x; cv2 = p.y;
  }
  int cand[4];
#pragma unroll
  for (int rsel = 0; rsel < 4; ++rsel) {
    float bv = cv;
#pragma unroll
    for (int mask = 1; mask < 8; mask <<= 1)
      bv = fminf(bv, __shfl_xor(bv, mask, 64));
    bv = __shfl(bv, 0, 64);
    cand[rsel] = (int)(__float_as_uint(bv) & 8191u);
    if (cv == bv) { cv = cv2; cv2 = INFINITY; }
  }
  const float4 xv = *(const float4*)(x + (size_t)row * DIM + lane * 4);
  float4 q0 = *(const float4*)(cb + (size_t)cand[0] * DIM + lane * 4);
  float4 q1 = *(const float4*)(cb + (size_t)cand[1] * DIM + lane * 4);
  float4 q2 = *(const float4*)(cb + (size_t)cand[2] * DIM + lane * 4);
  float4 q3 = *(const float4*)(cb + (size_t)cand[3] * DIM + lane * 4);
  float d0 = xv.x * q0.x + xv.y * q0.y + xv.z * q0.z + xv.w * q0.w;
  float d1 = xv.x * q1.x + xv.y * q1.y + xv.z * q1.z + xv.w * q1.w;
  float d2 = xv.x * q2.x + xv.y * q2.y + xv.z * q2.z + xv.w * q2.w;
  float d3 = xv.x * q3.x + xv.y * q3.y + xv.z * q3.z + xv.w * q3.w;
  float x2 = xv.x * xv.x + xv.y * xv.y + xv.z * xv.z + xv.w * xv.w;
#pragma unroll
  for (int mask = 1; mask < 64; mask <<= 1) {
    d0 += __shfl_xor(d0, mask, 64);
    d1 += __shfl_xor(d1, mask, 64);
    d2 += __shfl_xor(d2, mask, 64);
    d3 += __shfl_xor(d3, mask, 64);
    x2 += __shfl_xor(x2, mask, 64);
  }
  float e0 = fmaf(-2.0f, d0, c2g[cand[0]]);
  float e1 = fmaf(-2.0f, d1, c2g[cand[1]]);
  float e2 = fmaf(-2.0f, d2, c2g[cand[2]]);
  float e3 = fmaf(-2.0f, d3, c2g[cand[3]]);
  float best = e0; int bk = cand[0];
  if (e1 < best || (e1 == best && cand[1] < bk)) { best = e1; bk = cand[1]; }
  if (e2 < best || (e2 == best && cand[2] < bk)) { best = e2; bk = cand[2]; }
  if (e3 < best || (e3 == best && cand[3] < bk)) { best = e3; bk = cand[3]; }
  float4 q = (bk == cand[1]) ? q1 : (bk == cand[2]) ? q2 : (bk == cand[3]) ? q3 : q0;
  *(float4*)(out_q + (size_t)row * DIM + lane * 4) = q;
  if (lane == 0) {
    ind[row] = bk;
    out_ind[row] = (float)bk;
    atomicAdd(cnt + bk, 1);
    lsm[wid] = x2 + best;   // == ||q - x||^2 (exact identity)
  }
  __syncthreads();
  if (threadIdx.x == 0)
    loss_part[blockIdx.x] = lsm[0] + lsm[1] + lsm[2] + lsm[3];
}

// ---- scan: exclusive scan cnt -> offs/woffs; out_cs; reduce loss ----
__global__ __launch_bounds__(1024)
void vq_scan(const int* __restrict__ cnt, int* __restrict__ offs,
             int* __restrict__ woffs, float* __restrict__ out_cs,
             const float* __restrict__ loss_part, float* __restrict__ out_loss) {
  __shared__ int ssum[1024];
  __shared__ float sls[1024];
  int tid = threadIdx.x;
  int c[8], loc[8];
  int s = 0;
#pragma unroll
  for (int j = 0; j < 8; ++j) {
    c[j] = cnt[tid * 8 + j];
    loc[j] = s;
    s += c[j];
  }
  ssum[tid] = s;
  float ls = 0.0f;
#pragma unroll
  for (int j = 0; j < 8; ++j) ls += loss_part[tid * 8 + j];
  sls[tid] = ls;
  __syncthreads();
  for (int off = 1; off < 1024; off <<= 1) {
    int v = (tid >= off) ? ssum[tid - off] : 0;
    __syncthreads();
    ssum[tid] += v;
    __syncthreads();
  }
  int base = (tid > 0) ? ssum[tid - 1] : 0;
#pragma unroll
  for (int j = 0; j < 8; ++j) {
    int o = base + loc[j];
    offs[tid * 8 + j] = o;
    woffs[tid * 8 + j] = o;
    out_cs[tid * 8 + j] = (float)c[j];
  }
  for (int off = 512; off >= 1; off >>= 1) {
    if (tid < off) sls[tid] += sls[tid + off];
    __syncthreads();
  }
  if (tid == 0) *out_loss = sls[0] * (1.0f / 8388608.0f);
}

// ---- scatter: build rowlist grouped by code ----
__global__ __launch_bounds__(256)
void vq_scatter(const int* __restrict__ ind, int* __restrict__ woffs,
                int* __restrict__ rowlist) {
  int row = blockIdx.x * 256 + threadIdx.x;
  int k = ind[row];
  int pos = atomicAdd(woffs + k, 1);
  rowlist[pos] = row;
}

// ---- esum: ONE BLOCK (4 waves) PER CODE; unroll-4 ILP; LDS cross-wave ----
__global__ __launch_bounds__(256)
void vq_esum(const float* __restrict__ x, const int* __restrict__ offs,
             const int* __restrict__ cnt, const int* __restrict__ rowlist,
             float* __restrict__ out_es) {
  __shared__ float4 sred[3][64];
  int k = blockIdx.x;
  int wid = threadIdx.x >> 6, lane = threadIdx.x & 63;
  int start = offs[k], n = cnt[k];
  const int* rl = rowlist + start;
  int jb = (n * wid) >> 2, je = (n * (wid + 1)) >> 2;
  float4 acc = {0.f, 0.f, 0.f, 0.f};
  int j = jb;
  for (; j + 4 <= je; j += 4) {
    int r0 = rl[j], r1 = rl[j + 1], r2 = rl[j + 2], r3 = rl[j + 3];
    float4 v0 = *(const float4*)(x + (size_t)r0 * DIM + lane * 4);
    float4 v1 = *(const float4*)(x + (size_t)r1 * DIM + lane * 4);
    float4 v2 = *(const float4*)(x + (size_t)r2 * DIM + lane * 4);
    float4 v3 = *(const float4*)(x + (size_t)r3 * DIM + lane * 4);
    acc.x += v0.x + v1.x + v2.x + v3.x;
    acc.y += v0.y + v1.y + v2.y + v3.y;
    acc.z += v0.z + v1.z + v2.z + v3.z;
    acc.w += v0.w + v1.w + v2.w + v3.w;
  }
  for (; j < je; ++j) {
    int r = rl[j];
    float4 v = *(const float4*)(x + (size_t)r * DIM + lane * 4);
    acc.x += v.x; acc.y += v.y; acc.z += v.z; acc.w += v.w;
  }
  if (wid > 0) sred[wid - 1][lane] = acc;
  __syncthreads();
  if (wid == 0) {
    float4 a1 = sred[0][lane], a2 = sred[1][lane], a3 = sred[2][lane];
    acc.x += a1.x + a2.x + a3.x;
    acc.y += a1.y + a2.y + a3.y;
    acc.z += a1.z + a2.z + a3.z;
    acc.w += a1.w + a2.w + a3.w;
    *(float4*)(out_es + (size_t)k * DIM + lane * 4) = acc;
  }
}

extern "C" void kernel_launch(void* const* d_in, const int* in_sizes, int n_in,
                              void* d_out, int out_size, void* d_ws,
                              size_t ws_size, hipStream_t stream) {
  const float* x = (const float*)d_in[0];
  const float* cb = (const float*)d_in[1];
  float* out = (float*)d_out;
  float* out_q = out;
  float* out_ind = out + OUT_IND;
  float* out_loss = out + OUT_LOSS;
  float* out_cs = out + OUT_CS;
  float* out_es = out + OUT_ES;

  // Scratch-in-output (same proven layout as rounds 7-11):
  u16* Abuf = (u16*)(out + ABUF_OFF);
  u16* CBb = (u16*)(out + CBB_OFF);
  float2* partials = (float2*)(out + PART_OFF);

  // ws layout (448 KB; >= 2.21 MB proven available in round 1)
  char* w = (char*)d_ws;
  int* cnt = (int*)w;                              // 32 KB [memset 0]
  int* offs = (int*)(w + (32 << 10));              // 32 KB
  int* woffs = (int*)(w + (64 << 10));             // 32 KB
  float* loss_part = (float*)(w + (96 << 10));     // 32 KB
  int* ind = (int*)(w + (128 << 10));              // 128 KB
  int* rowlist = (int*)(w + (256 << 10));          // 128 KB
  float* c2 = (float*)(w + (384 << 10));           // 32 KB
  float* c2m = (float*)(w + (416 << 10));          // 32 KB

  hipMemsetAsync(cnt, 0, KCODES * sizeof(int), stream);
  vq_prep<<<5120, 256, 0, stream>>>(x, cb, Abuf, CBb, c2, c2m);
  vq_mfma<<<256 * NSPLIT, 256, 0, stream>>>(Abuf, CBb, c2m, partials);
  vq_pick<<<BN_TOTAL / 4, 256, 0, stream>>>(x, cb, c2, partials, ind, out_ind,
                                            out_q, cnt, loss_part);
  vq_scan<<<1, 1024, 0, stream>>>(cnt, offs, woffs, out_cs, loss_part, out_loss);
  vq_scatter<<<BN_TOTAL / 256, 256, 0, stream>>>(ind, woffs, rowlist);
  vq_esum<<<KCODES, 256, 0, stream>>>(x, offs, cnt, rowlist, out_es);
}